// Round 17
// baseline (236.819 us; speedup 1.0000x reference)
//
#include <hip/hip_runtime.h>

#define N_NODES 100000
#define EMB 128
#define NE 800000            // edges per edge set (pos / neg)
#define NEDGES (2 * NE)      // total edges

// windowed counting sort for CSR fill
#define NWIN 256
#define WNODES 391           // 256*391 = 100096 >= N_NODES
#define WCAP 8192            // padded per-window capacity (mean 6250, +24 sigma)
#define ACHUNK 2048          // edges per binA block (782 blocks -> ~3 blocks/CU)
#define ABLOCKS ((NEDGES + ACHUNK - 1) / ACHUNK)                // 782
#define SEGCAP 7000          // per-window record capacity (mean 6256, +9 sigma)

typedef __attribute__((ext_vector_type(8))) short bf16x8;
typedef __attribute__((ext_vector_type(4))) float f32x4;
typedef __attribute__((ext_vector_type(2))) float f32x2;

// ---------------- utility ----------------

__device__ __forceinline__ unsigned short f2bf(float f) {
    unsigned u = __builtin_bit_cast(unsigned, f);
    u += 0x7FFFu + ((u >> 16) & 1u);          // round-to-nearest-even
    return (unsigned short)(u >> 16);
}

__device__ __forceinline__ unsigned pk2bf(float lo, float hi) {
    return (unsigned)f2bf(lo) | ((unsigned)f2bf(hi) << 16);
}

__device__ __forceinline__ float bflo(unsigned u) { return __builtin_bit_cast(float, u << 16); }
__device__ __forceinline__ float bfhi(unsigned u) { return __builtin_bit_cast(float, u & 0xFFFF0000u); }

__device__ __forceinline__ f32x2 unpk2(unsigned u) {
    f32x2 r;
    r.x = bflo(u);
    r.y = bfhi(u);
    return r;
}

__global__ void binit_kernel(int* __restrict__ bcur) {
    int w = threadIdx.x;
    if (w < NWIN) bcur[w] = w * WCAP;
}

// ---- Phase A: bin edges by dst-window into padded regions ----
// temp record: (d - w*WNODES) << 17 | src.
// Single global read of the edge list; LDS-staged arrival->sorted permute.

__global__ __launch_bounds__(256) void binA_kernel(const int* __restrict__ pos,
                                                   const int* __restrict__ neg,
                                                   int* __restrict__ bucket_cursor,
                                                   unsigned* __restrict__ ptmp) {
    __shared__ int lcnt[NWIN];
    __shared__ int lofs[NWIN];
    __shared__ int lcur[NWIN];
    __shared__ int gbase[NWIN];
    __shared__ int stmp[NWIN];
    __shared__ unsigned abuf[ACHUNK];        // arrival-order records
    __shared__ unsigned char awin[ACHUNK];   // arrival-order window ids
    __shared__ unsigned pbuf2[ACHUNK];       // sorted records
    __shared__ unsigned char wbuf2[ACHUNK];  // sorted window ids

    const int tid  = threadIdx.x;
    const int e0   = blockIdx.x * ACHUNK;
    const int ecnt = (NEDGES - e0 < ACHUNK) ? (NEDGES - e0) : ACHUNK;

    if (tid < NWIN) lcnt[tid] = 0;
    __syncthreads();

    // pass 1: single global read, stage in LDS + window histogram
    for (int k = tid; k < ecnt; k += 256) {
        int i = e0 + k;
        int s, d;
        if (i < NE) { s = pos[i];      d = pos[NE + i]; }
        else        { s = neg[i - NE]; d = neg[i]; }
        int w = d / WNODES;
        abuf[k] = ((unsigned)(d - w * WNODES) << 17) | (unsigned)s;
        awin[k] = (unsigned char)w;
        atomicAdd(&lcnt[w], 1);
    }
    __syncthreads();

    // parallel Hillis-Steele inclusive scan of lcnt
    if (tid < NWIN) stmp[tid] = lcnt[tid];
    __syncthreads();
    for (int off = 1; off < NWIN; off <<= 1) {
        int v = (tid < NWIN && tid >= off) ? stmp[tid - off] : 0;
        __syncthreads();
        if (tid < NWIN) stmp[tid] += v;
        __syncthreads();
    }
    if (tid < NWIN) {
        lofs[tid]  = stmp[tid] - lcnt[tid];
        lcur[tid]  = stmp[tid] - lcnt[tid];
        gbase[tid] = atomicAdd(&bucket_cursor[tid], lcnt[tid]);
    }
    __syncthreads();

    // pass 2: LDS permute arrival -> window-sorted
    for (int k = tid; k < ecnt; k += 256) {
        int w = awin[k];
        int lp = atomicAdd(&lcur[w], 1);
        pbuf2[lp] = abuf[k];
        wbuf2[lp] = (unsigned char)w;
    }
    __syncthreads();

    // pass 3: contiguous copy-out per window
    for (int k = tid; k < ecnt; k += 256) {
        int w = wbuf2[k];
        ptmp[gbase[w] + (k - lofs[w])] = pbuf2[k];
    }
}

// ---- window-base scan ----

__global__ __launch_bounds__(NWIN) void wscan_kernel(const int* __restrict__ bcur,
                                                     int* __restrict__ wbase) {
    __shared__ int sc[NWIN];
    const int tid = threadIdx.x;
    int t = bcur[tid] - tid * WCAP;
    sc[tid] = t;
    __syncthreads();
    for (int off = 1; off < NWIN; off <<= 1) {
        int v = (tid >= off) ? sc[tid - off] : 0;
        __syncthreads();
        sc[tid] += v;
        __syncthreads();
    }
    wbase[tid] = sc[tid] - t;
}

// ---- Phase CB (fused): LDS-staged single-read histogram + scan -> rowptr/dtab,
//      scatter to CSR order in LDS, sequential writeback.
//      colidx record = src + 1 (0 is the invalid sentinel; dtab[0] = 0).

__global__ __launch_bounds__(1024) void binCB_kernel(const int* __restrict__ bcur,
                                                     const int* __restrict__ wbase,
                                                     const unsigned* __restrict__ ptmp,
                                                     int* __restrict__ rowptr,
                                                     float* __restrict__ dtab,
                                                     unsigned* __restrict__ colidx) {
    __shared__ int cnt[WNODES];
    __shared__ int sc[512];
    __shared__ unsigned stage[WCAP];      // 32 KB: records staged on first read
    __shared__ unsigned colseg[SEGCAP];   // 28 KB

    const int w   = blockIdx.x;
    const int lo  = w * WNODES;
    const int hi  = (lo + WNODES < N_NODES) ? lo + WNODES : N_NODES;
    const int nn  = hi - lo;
    const int tot = bcur[w] - w * WCAP;
    const int tid = threadIdx.x;
    const unsigned* __restrict__ rp = ptmp + (size_t)w * WCAP;

    for (int k = tid; k < nn; k += 1024) cnt[k] = 0;
    __syncthreads();

    // pass 1: single global read, stage + per-node histogram
    for (int k = tid; k < tot; k += 1024) {
        unsigned v = rp[k];
        stage[k] = v;
        atomicAdd(&cnt[v >> 17], 1);
    }
    __syncthreads();

    // inclusive scan over nodes
    if (tid < 512) sc[tid] = (tid < nn) ? cnt[tid] : 0;
    __syncthreads();
    for (int off = 1; off < 512; off <<= 1) {
        int v = (tid < 512 && tid >= off) ? sc[tid - off] : 0;
        __syncthreads();
        if (tid < 512) sc[tid] += v;
        __syncthreads();
    }

    const int base = wbase[w];
    int myexc = 0;
    if (tid < nn) {
        myexc = sc[tid] - cnt[tid];                 // exclusive prefix
        rowptr[lo + tid]   = base + myexc;
        dtab[lo + tid + 1] = rsqrtf((float)cnt[tid] + 1.0f);  // +1 self-loop
    }
    if (w == 0 && tid == 0) { rowptr[N_NODES] = NEDGES; dtab[0] = 0.0f; }
    __syncthreads();

    // reuse cnt[] as scatter cursors
    if (tid < nn) cnt[tid] = myexc;
    __syncthreads();

    // pass 2: scatter from LDS stage into CSR order (src+1)
    for (int k = tid; k < tot; k += 1024) {
        unsigned v = stage[k];
        int dl = v >> 17;
        unsigned s = (v & 0x1FFFFu) + 1u;
        int lp = atomicAdd(&cnt[dl], 1);
        if (lp < SEGCAP) colseg[lp] = s;
    }
    __syncthreads();

    // pass 3: sequential writeback
    for (int k = tid; k < tot; k += 1024) colidx[base + k] = colseg[k];
}

// ---------------- GEMM (MFMA bf16): Hb[N][128] = bf16(Xin @ W) ----------------

#define GROWS 64

template<bool BF16IN>
__global__ __launch_bounds__(256) void gemm_kernel(const void* __restrict__ Xin,
                                                   const float* __restrict__ W,
                                                   unsigned short* __restrict__ Hb) {
    __shared__ unsigned short Wb[128 * 128];   // 32 KB

    const int tid  = threadIdx.x;
    const int row0 = blockIdx.x * GROWS;

    for (int i = tid * 4; i < 128 * 128; i += 256 * 4) {
        float4 v = *(const float4*)&W[i];
        int k = i >> 7;
        int c = i & 127;
        int ks = k >> 5;
        int kg = (k >> 3) & 3;
        int j  = k & 7;
        float vv[4] = {v.x, v.y, v.z, v.w};
#pragma unroll
        for (int q = 0; q < 4; ++q) {
            int cc   = c + q;
            int ct   = cc >> 4;
            int lane = (cc & 15) + 16 * kg;
            Wb[((ct * 4 + ks) * 64 + lane) * 8 + j] = f2bf(vv[q]);
        }
    }
    __syncthreads();

    const int wave = tid >> 6;
    const int lane = tid & 63;
    const int r    = lane & 15;
    const int kg   = lane >> 4;

    int row = row0 + wave * 16 + r;
    int rowc = (row < N_NODES) ? row : N_NODES - 1;

    bf16x8 a[4];
    if (BF16IN) {
        const unsigned short* Xb = (const unsigned short*)Xin;
#pragma unroll
        for (int ks = 0; ks < 4; ++ks) {
            a[ks] = *(const bf16x8*)&Xb[(size_t)rowc * EMB + ks * 32 + kg * 8];
        }
    } else {
        const float* Xf = (const float*)Xin;
#pragma unroll
        for (int ks = 0; ks < 4; ++ks) {
            const float4* p = (const float4*)&Xf[(size_t)rowc * EMB + ks * 32 + kg * 8];
            float4 u = p[0];
            float4 v = p[1];
            bf16x8 av;
            av[0] = (short)f2bf(u.x); av[1] = (short)f2bf(u.y);
            av[2] = (short)f2bf(u.z); av[3] = (short)f2bf(u.w);
            av[4] = (short)f2bf(v.x); av[5] = (short)f2bf(v.y);
            av[6] = (short)f2bf(v.z); av[7] = (short)f2bf(v.w);
            a[ks] = av;
        }
    }

    f32x4 acc[8];
#pragma unroll
    for (int ct = 0; ct < 8; ++ct) acc[ct] = (f32x4){0.f, 0.f, 0.f, 0.f};

#pragma unroll
    for (int ct = 0; ct < 8; ++ct) {
#pragma unroll
        for (int ks = 0; ks < 4; ++ks) {
            bf16x8 b = *(bf16x8*)&Wb[((ct * 4 + ks) * 64 + lane) * 8];
            acc[ct] = __builtin_amdgcn_mfma_f32_16x16x32_bf16(a[ks], b, acc[ct], 0, 0, 0);
        }
    }

    const int orow0 = row0 + wave * 16 + (lane >> 4) * 4;
    const int oc    = lane & 15;
#pragma unroll
    for (int reg = 0; reg < 4; ++reg) {
        int orow = orow0 + reg;
        if (orow < N_NODES) {
#pragma unroll
            for (int ct = 0; ct < 8; ++ct) {
                Hb[(size_t)orow * EMB + ct * 16 + oc] = f2bf(acc[ct][reg]);
            }
        }
    }
}

// ---------------- fused aggregate v8 ----------------
// out[n] = dd * sum_e dinv[src]*h[src] + dd^2*h[n] + b   (dd factored out).
// rec = src+1 (0 = invalid sentinel); dtab[0]=0, dtab[s+1]=dinv[s] (L2-resident).

#define AGG_WAVES 4

template<bool STORE_BF16>
__global__ __launch_bounds__(256) void aggregate_kernel(const int* __restrict__ rowptr,
                                                        const unsigned* __restrict__ rec,
                                                        const unsigned* __restrict__ Hb32,
                                                        const float* __restrict__ dtab,
                                                        const float* __restrict__ bias,
                                                        void* __restrict__ outv) {
    const int wave = threadIdx.x >> 6;
    const int lane = threadIdx.x & 63;
    const int node = blockIdx.x * AGG_WAVES + wave;
    if (node >= N_NODES) return;

    const int sub  = lane >> 4;           // 0..3
    const int dl   = lane & 15;           // 0..15
    const unsigned dlo = (unsigned)(dl << 4);

    const int start = rowptr[node];
    const int end   = rowptr[node + 1];

    f32x2 acc2[4];
#pragma unroll
    for (int j = 0; j < 4; ++j) acc2[j] = (f32x2){0.f, 0.f};

    const char* __restrict__ hbase = (const char*)Hb32;

    for (int b = start; b < end; b += 64) {
        int li = b + lane;
        unsigned rl = 0;
        if (li < end) rl = rec[li];       // 0 sentinel => dtab[0]=0, row 0 gathered harmlessly
        int nb = end - b; if (nb > 64) nb = 64;
        for (int i = 0; i < nb; i += 16) {
            unsigned rA = __shfl(rl, i + sub,      64);
            unsigned rB = __shfl(rl, i + 4 + sub,  64);
            unsigned rC = __shfl(rl, i + 8 + sub,  64);
            unsigned rD = __shfl(rl, i + 12 + sub, 64);
            float nA = dtab[rA];
            float nB = dtab[rB];
            float nC = dtab[rC];
            float nD = dtab[rD];
            unsigned oA = rA ? (((rA - 1u) << 8) | dlo) : dlo;
            unsigned oB = rB ? (((rB - 1u) << 8) | dlo) : dlo;
            unsigned oC = rC ? (((rC - 1u) << 8) | dlo) : dlo;
            unsigned oD = rD ? (((rD - 1u) << 8) | dlo) : dlo;
            uint4 qA = *(const uint4*)(hbase + oA);
            uint4 qB = *(const uint4*)(hbase + oB);
            uint4 qC = *(const uint4*)(hbase + oC);
            uint4 qD = *(const uint4*)(hbase + oD);
            f32x2 nA2 = (f32x2){nA, nA};
            f32x2 nB2 = (f32x2){nB, nB};
            f32x2 nC2 = (f32x2){nC, nC};
            f32x2 nD2 = (f32x2){nD, nD};
            acc2[0] = __builtin_elementwise_fma(nA2, unpk2(qA.x), acc2[0]);
            acc2[1] = __builtin_elementwise_fma(nA2, unpk2(qA.y), acc2[1]);
            acc2[2] = __builtin_elementwise_fma(nA2, unpk2(qA.z), acc2[2]);
            acc2[3] = __builtin_elementwise_fma(nA2, unpk2(qA.w), acc2[3]);
            acc2[0] = __builtin_elementwise_fma(nB2, unpk2(qB.x), acc2[0]);
            acc2[1] = __builtin_elementwise_fma(nB2, unpk2(qB.y), acc2[1]);
            acc2[2] = __builtin_elementwise_fma(nB2, unpk2(qB.z), acc2[2]);
            acc2[3] = __builtin_elementwise_fma(nB2, unpk2(qB.w), acc2[3]);
            acc2[0] = __builtin_elementwise_fma(nC2, unpk2(qC.x), acc2[0]);
            acc2[1] = __builtin_elementwise_fma(nC2, unpk2(qC.y), acc2[1]);
            acc2[2] = __builtin_elementwise_fma(nC2, unpk2(qC.z), acc2[2]);
            acc2[3] = __builtin_elementwise_fma(nC2, unpk2(qC.w), acc2[3]);
            acc2[0] = __builtin_elementwise_fma(nD2, unpk2(qD.x), acc2[0]);
            acc2[1] = __builtin_elementwise_fma(nD2, unpk2(qD.y), acc2[1]);
            acc2[2] = __builtin_elementwise_fma(nD2, unpk2(qD.z), acc2[2]);
            acc2[3] = __builtin_elementwise_fma(nD2, unpk2(qD.w), acc2[3]);
        }
    }

    float acc[8];
#pragma unroll
    for (int j = 0; j < 4; ++j) { acc[2 * j] = acc2[j].x; acc[2 * j + 1] = acc2[j].y; }

#pragma unroll
    for (int j = 0; j < 8; ++j) {
        acc[j] += __shfl_xor(acc[j], 16, 64);
        acc[j] += __shfl_xor(acc[j], 32, 64);
    }

    if (sub == 0) {
        const float dd = dtab[node + 1];
        const float s2 = dd * dd;
        uint4 q = *(const uint4*)(hbase + (((unsigned)node << 8) | dlo));
        float o[8];
        o[0] = dd * acc[0] + s2 * bflo(q.x);
        o[1] = dd * acc[1] + s2 * bfhi(q.x);
        o[2] = dd * acc[2] + s2 * bflo(q.y);
        o[3] = dd * acc[3] + s2 * bfhi(q.y);
        o[4] = dd * acc[4] + s2 * bflo(q.z);
        o[5] = dd * acc[5] + s2 * bfhi(q.z);
        o[6] = dd * acc[6] + s2 * bflo(q.w);
        o[7] = dd * acc[7] + s2 * bfhi(q.w);

        float4 b0 = *(const float4*)&bias[dl * 8];
        float4 b1 = *(const float4*)&bias[dl * 8 + 4];
        o[0] += b0.x; o[1] += b0.y; o[2] += b0.z; o[3] += b0.w;
        o[4] += b1.x; o[5] += b1.y; o[6] += b1.z; o[7] += b1.w;

        if (STORE_BF16) {
            unsigned short* ob = (unsigned short*)outv;
            uint4 pk;
            pk.x = pk2bf(o[0], o[1]);
            pk.y = pk2bf(o[2], o[3]);
            pk.z = pk2bf(o[4], o[5]);
            pk.w = pk2bf(o[6], o[7]);
            *(uint4*)&ob[(size_t)node * EMB + dl * 8] = pk;
        } else {
            float* of = (float*)outv;
            *(float4*)&of[(size_t)node * EMB + dl * 8]     = make_float4(o[0], o[1], o[2], o[3]);
            *(float4*)&of[(size_t)node * EMB + dl * 8 + 4] = make_float4(o[4], o[5], o[6], o[7]);
        }
    }
}

// ---------------- launch ----------------

extern "C" void kernel_launch(void* const* d_in, const int* in_sizes, int n_in,
                              void* d_out, int out_size, void* d_ws, size_t ws_size,
                              hipStream_t stream) {
    const float* x  = (const float*)d_in[0];
    const float* W0 = (const float*)d_in[1];
    const float* b0 = (const float*)d_in[2];
    const float* W1 = (const float*)d_in[3];
    const float* b1 = (const float*)d_in[4];
    const int*   pos = (const int*)d_in[5];
    const int*   neg = (const int*)d_in[6];

    // workspace layout (4-byte units)
    float* ws      = (float*)d_ws;
    float* dtab    = ws;                                  // 100001 (dtab[0]=0)
    unsigned short* hb = (unsigned short*)(ws + 100352);  // [N][128] bf16
    int*   rowptr  = (int*)(ws + 6500352);                // 100001
    int*   bcur    = (int*)(ws + 6600356);                // 256
    int*   wbase   = (int*)(ws + 6600612);                // 256
    unsigned* ptmp = (unsigned*)(ws + 6600872);           // 256*8192
    unsigned* colidx = (unsigned*)(ws + 8698024);         // 1.6M records (src+1)
    unsigned short* zb = (unsigned short*)(ws + 10298024);// [N][128] bf16 (layer-0 z)

    // ---- CSR build (shared by both layers) ----
    binit_kernel<<<1, NWIN, 0, stream>>>(bcur);
    binA_kernel<<<ABLOCKS, 256, 0, stream>>>(pos, neg, bcur, ptmp);
    wscan_kernel<<<1, NWIN, 0, stream>>>(bcur, wbase);
    binCB_kernel<<<NWIN, 1024, 0, stream>>>(bcur, wbase, ptmp, rowptr, dtab, colidx);

    const int agg_grid  = (N_NODES + AGG_WAVES - 1) / AGG_WAVES;
    const int gemm_grid = (N_NODES + GROWS - 1) / GROWS;

    // ---- layer 0: h0 = bf16(x@W0); z0(bf16) = agg(h0) + b0 ----
    gemm_kernel<false><<<gemm_grid, 256, 0, stream>>>(x, W0, hb);
    aggregate_kernel<true><<<agg_grid, 256, 0, stream>>>(
        rowptr, colidx, (const unsigned*)hb, dtab, b0, zb);

    // ---- layer 1: h1 = bf16(z0@W1); out(f32) = agg(h1) + b1 ----
    gemm_kernel<true><<<gemm_grid, 256, 0, stream>>>(zb, W1, hb);
    aggregate_kernel<false><<<agg_grid, 256, 0, stream>>>(
        rowptr, colidx, (const unsigned*)hb, dtab, b1, d_out);
}

// Round 19
// 206.589 us; speedup vs baseline: 1.1463x; 1.1463x over previous
//
#include <hip/hip_runtime.h>

#define N_NODES 100000
#define EMB 128
#define NE 800000            // edges per edge set (pos / neg)
#define NEDGES (2 * NE)      // total edges

// windowed counting sort for CSR fill
#define NWIN 256
#define WNODES 391           // 256*391 = 100096 >= N_NODES
#define WCAP 8192            // padded per-window capacity
#define ACHUNK 2048          // edges per binA block (782 blocks)
#define ABLOCKS ((NEDGES + ACHUNK - 1) / ACHUNK)                // 782
#define SEGCAP 7000          // per-window record capacity

typedef __attribute__((ext_vector_type(8))) short bf16x8;
typedef __attribute__((ext_vector_type(4))) float f32x4;
typedef __attribute__((ext_vector_type(2))) float f32x2;

// ---------------- utility ----------------

__device__ __forceinline__ unsigned short f2bf(float f) {
    unsigned u = __builtin_bit_cast(unsigned, f);
    u += 0x7FFFu + ((u >> 16) & 1u);          // round-to-nearest-even
    return (unsigned short)(u >> 16);
}

__device__ __forceinline__ unsigned pk2bf(float lo, float hi) {
    return (unsigned)f2bf(lo) | ((unsigned)f2bf(hi) << 16);
}

__device__ __forceinline__ float bflo(unsigned u) { return __builtin_bit_cast(float, u << 16); }
__device__ __forceinline__ float bfhi(unsigned u) { return __builtin_bit_cast(float, u & 0xFFFF0000u); }

__device__ __forceinline__ f32x2 unpk2(unsigned u) {
    f32x2 r;
    r.x = bflo(u);
    r.y = bfhi(u);
    return r;
}

__global__ void binit_kernel(int* __restrict__ bcur) {
    int w = threadIdx.x;
    if (w < NWIN) bcur[w] = w * WCAP;
}

// ---- Phase A: bin edges by dst-window into padded regions ----

__global__ __launch_bounds__(256) void binA_kernel(const int* __restrict__ pos,
                                                   const int* __restrict__ neg,
                                                   int* __restrict__ bucket_cursor,
                                                   unsigned* __restrict__ ptmp) {
    __shared__ int lcnt[NWIN];
    __shared__ int lofs[NWIN];
    __shared__ int lcur[NWIN];
    __shared__ int gbase[NWIN];
    __shared__ int stmp[NWIN];
    __shared__ unsigned abuf[ACHUNK];
    __shared__ unsigned char awin[ACHUNK];
    __shared__ unsigned pbuf2[ACHUNK];
    __shared__ unsigned char wbuf2[ACHUNK];

    const int tid  = threadIdx.x;
    const int e0   = blockIdx.x * ACHUNK;
    const int ecnt = (NEDGES - e0 < ACHUNK) ? (NEDGES - e0) : ACHUNK;

    if (tid < NWIN) lcnt[tid] = 0;
    __syncthreads();

    for (int k = tid; k < ecnt; k += 256) {
        int i = e0 + k;
        int s, d;
        if (i < NE) { s = pos[i];      d = pos[NE + i]; }
        else        { s = neg[i - NE]; d = neg[i]; }
        int w = d / WNODES;
        abuf[k] = ((unsigned)(d - w * WNODES) << 17) | (unsigned)s;
        awin[k] = (unsigned char)w;
        atomicAdd(&lcnt[w], 1);
    }
    __syncthreads();

    if (tid < NWIN) stmp[tid] = lcnt[tid];
    __syncthreads();
    for (int off = 1; off < NWIN; off <<= 1) {
        int v = (tid < NWIN && tid >= off) ? stmp[tid - off] : 0;
        __syncthreads();
        if (tid < NWIN) stmp[tid] += v;
        __syncthreads();
    }
    if (tid < NWIN) {
        lofs[tid]  = stmp[tid] - lcnt[tid];
        lcur[tid]  = stmp[tid] - lcnt[tid];
        gbase[tid] = atomicAdd(&bucket_cursor[tid], lcnt[tid]);
    }
    __syncthreads();

    for (int k = tid; k < ecnt; k += 256) {
        int w = awin[k];
        int lp = atomicAdd(&lcur[w], 1);
        pbuf2[lp] = abuf[k];
        wbuf2[lp] = (unsigned char)w;
    }
    __syncthreads();

    for (int k = tid; k < ecnt; k += 256) {
        int w = wbuf2[k];
        ptmp[gbase[w] + (k - lofs[w])] = pbuf2[k];
    }
}

// ---- window-base scan ----

__global__ __launch_bounds__(NWIN) void wscan_kernel(const int* __restrict__ bcur,
                                                     int* __restrict__ wbase) {
    __shared__ int sc[NWIN];
    const int tid = threadIdx.x;
    int t = bcur[tid] - tid * WCAP;
    sc[tid] = t;
    __syncthreads();
    for (int off = 1; off < NWIN; off <<= 1) {
        int v = (tid >= off) ? sc[tid - off] : 0;
        __syncthreads();
        sc[tid] += v;
        __syncthreads();
    }
    wbase[tid] = sc[tid] - t;
}

// ---- Phase CB (fused) ----

__global__ __launch_bounds__(1024) void binCB_kernel(const int* __restrict__ bcur,
                                                     const int* __restrict__ wbase,
                                                     const unsigned* __restrict__ ptmp,
                                                     int* __restrict__ rowptr,
                                                     float* __restrict__ dtab,
                                                     unsigned* __restrict__ colidx) {
    __shared__ int cnt[WNODES];
    __shared__ int sc[512];
    __shared__ unsigned stage[WCAP];      // 32 KB
    __shared__ unsigned colseg[SEGCAP];   // 28 KB

    const int w   = blockIdx.x;
    const int lo  = w * WNODES;
    const int hi  = (lo + WNODES < N_NODES) ? lo + WNODES : N_NODES;
    const int nn  = hi - lo;
    const int tot = bcur[w] - w * WCAP;
    const int tid = threadIdx.x;
    const unsigned* __restrict__ rp = ptmp + (size_t)w * WCAP;

    for (int k = tid; k < nn; k += 1024) cnt[k] = 0;
    __syncthreads();

    for (int k = tid; k < tot; k += 1024) {
        unsigned v = rp[k];
        stage[k] = v;
        atomicAdd(&cnt[v >> 17], 1);
    }
    __syncthreads();

    if (tid < 512) sc[tid] = (tid < nn) ? cnt[tid] : 0;
    __syncthreads();
    for (int off = 1; off < 512; off <<= 1) {
        int v = (tid < 512 && tid >= off) ? sc[tid - off] : 0;
        __syncthreads();
        if (tid < 512) sc[tid] += v;
        __syncthreads();
    }

    const int base = wbase[w];
    int myexc = 0;
    if (tid < nn) {
        myexc = sc[tid] - cnt[tid];
        rowptr[lo + tid]   = base + myexc;
        dtab[lo + tid + 1] = rsqrtf((float)cnt[tid] + 1.0f);  // +1 self-loop
    }
    if (w == 0 && tid == 0) { rowptr[N_NODES] = NEDGES; dtab[0] = 0.0f; }
    __syncthreads();

    if (tid < nn) cnt[tid] = myexc;
    __syncthreads();

    for (int k = tid; k < tot; k += 1024) {
        unsigned v = stage[k];
        int dl = v >> 17;
        unsigned s = (v & 0x1FFFFu) + 1u;
        int lp = atomicAdd(&cnt[dl], 1);
        if (lp < SEGCAP) colseg[lp] = s;
    }
    __syncthreads();

    for (int k = tid; k < tot; k += 1024) colidx[base + k] = colseg[k];
}

// ---------------- W pre-swizzle: Wbg = bf16 B-fragment layout of W ----------------
// out index o (bf16): o = ((ct*4+ks)*64+lane)*8 + j, with
// k = ks*32 + (lane>>4)*8 + j, c = ct*16 + (lane&15). One uint (2 bf16) per thread.

__global__ __launch_bounds__(256) void wprep_kernel(const float* __restrict__ W,
                                                    unsigned* __restrict__ Wbg) {
    int o2 = blockIdx.x * 256 + threadIdx.x;   // 8192 uints total
    if (o2 >= 8192) return;
    int o    = o2 * 2;
    int ct   = o >> 11;
    int ks   = (o >> 9) & 3;
    int lane = (o >> 3) & 63;
    int j    = o & 7;                           // even
    int k    = ks * 32 + ((lane >> 4) << 3) + j;
    int c    = (ct << 4) + (lane & 15);
    float lo = W[k * 128 + c];
    float hi = W[(k + 1) * 128 + c];
    Wbg[o2] = pk2bf(lo, hi);
}

// ---------------- GEMM v5 (MFMA bf16): Hb[N][128] = bf16(Xin @ W) ----------------
// 128 rows/block = 4 waves x 2 row-tiles x 16 rows. Wb staged from pre-swizzled
// global via linear coalesced 32KB copy; B fragments shared across row-tiles.

#define GROWS 128

template<bool BF16IN>
__global__ __launch_bounds__(256) void gemm_kernel(const void* __restrict__ Xin,
                                                   const unsigned* __restrict__ Wbg,
                                                   unsigned short* __restrict__ Hb) {
    __shared__ unsigned short Wb[128 * 128];   // 32 KB

    const int tid  = threadIdx.x;
    const int row0 = blockIdx.x * GROWS;

    // linear coalesced stage: 2048 uint4
#pragma unroll
    for (int i = 0; i < 8; ++i) {
        int idx = tid + i * 256;
        ((uint4*)Wb)[idx] = ((const uint4*)Wbg)[idx];
    }
    __syncthreads();

    const int wave = tid >> 6;
    const int lane = tid & 63;
    const int r    = lane & 15;
    const int kg   = lane >> 4;

    int rowA = row0 + wave * 16 + r;
    int rowB = rowA + 64;
    int rowAc = (rowA < N_NODES) ? rowA : N_NODES - 1;
    int rowBc = (rowB < N_NODES) ? rowB : N_NODES - 1;

    bf16x8 a0[4], a1[4];
    if (BF16IN) {
        const unsigned short* Xb = (const unsigned short*)Xin;
#pragma unroll
        for (int ks = 0; ks < 4; ++ks) {
            a0[ks] = *(const bf16x8*)&Xb[(size_t)rowAc * EMB + ks * 32 + kg * 8];
            a1[ks] = *(const bf16x8*)&Xb[(size_t)rowBc * EMB + ks * 32 + kg * 8];
        }
    } else {
        const float* Xf = (const float*)Xin;
#pragma unroll
        for (int ks = 0; ks < 4; ++ks) {
            const float4* pA = (const float4*)&Xf[(size_t)rowAc * EMB + ks * 32 + kg * 8];
            const float4* pB = (const float4*)&Xf[(size_t)rowBc * EMB + ks * 32 + kg * 8];
            float4 uA = pA[0], vA = pA[1];
            float4 uB = pB[0], vB = pB[1];
            bf16x8 avA, avB;
            avA[0] = (short)f2bf(uA.x); avA[1] = (short)f2bf(uA.y);
            avA[2] = (short)f2bf(uA.z); avA[3] = (short)f2bf(uA.w);
            avA[4] = (short)f2bf(vA.x); avA[5] = (short)f2bf(vA.y);
            avA[6] = (short)f2bf(vA.z); avA[7] = (short)f2bf(vA.w);
            avB[0] = (short)f2bf(uB.x); avB[1] = (short)f2bf(uB.y);
            avB[2] = (short)f2bf(uB.z); avB[3] = (short)f2bf(uB.w);
            avB[4] = (short)f2bf(vB.x); avB[5] = (short)f2bf(vB.y);
            avB[6] = (short)f2bf(vB.z); avB[7] = (short)f2bf(vB.w);
            a0[ks] = avA;
            a1[ks] = avB;
        }
    }

    f32x4 acc0[8], acc1[8];
#pragma unroll
    for (int ct = 0; ct < 8; ++ct) {
        acc0[ct] = (f32x4){0.f, 0.f, 0.f, 0.f};
        acc1[ct] = (f32x4){0.f, 0.f, 0.f, 0.f};
    }

#pragma unroll
    for (int ct = 0; ct < 8; ++ct) {
#pragma unroll
        for (int ks = 0; ks < 4; ++ks) {
            bf16x8 b = *(bf16x8*)&Wb[((ct * 4 + ks) * 64 + lane) * 8];
            acc0[ct] = __builtin_amdgcn_mfma_f32_16x16x32_bf16(a0[ks], b, acc0[ct], 0, 0, 0);
            acc1[ct] = __builtin_amdgcn_mfma_f32_16x16x32_bf16(a1[ks], b, acc1[ct], 0, 0, 0);
        }
    }

    // write out: col = lane&15, rows (lane>>4)*4 + reg  per 16-row tile
    const int oc    = lane & 15;
    const int obase = row0 + wave * 16 + (lane >> 4) * 4;
#pragma unroll
    for (int reg = 0; reg < 4; ++reg) {
        int orowA = obase + reg;
        int orowB = orowA + 64;
        if (orowA < N_NODES) {
#pragma unroll
            for (int ct = 0; ct < 8; ++ct)
                Hb[(size_t)orowA * EMB + ct * 16 + oc] = f2bf(acc0[ct][reg]);
        }
        if (orowB < N_NODES) {
#pragma unroll
            for (int ct = 0; ct < 8; ++ct)
                Hb[(size_t)orowB * EMB + ct * 16 + oc] = f2bf(acc1[ct][reg]);
        }
    }
}

// ---------------- fused aggregate v8 ----------------
// out[n] = dd * sum_e dinv[src]*h[src] + dd^2*h[n] + b   (dd factored out).
// rec = src+1 (0 = invalid sentinel); dtab[0]=0, dtab[s+1]=dinv[s].

#define AGG_WAVES 4

template<bool STORE_BF16>
__global__ __launch_bounds__(256) void aggregate_kernel(const int* __restrict__ rowptr,
                                                        const unsigned* __restrict__ rec,
                                                        const unsigned* __restrict__ Hb32,
                                                        const float* __restrict__ dtab,
                                                        const float* __restrict__ bias,
                                                        void* __restrict__ outv) {
    const int wave = threadIdx.x >> 6;
    const int lane = threadIdx.x & 63;
    const int node = blockIdx.x * AGG_WAVES + wave;
    if (node >= N_NODES) return;

    const int sub  = lane >> 4;           // 0..3
    const int dl   = lane & 15;           // 0..15
    const unsigned dlo = (unsigned)(dl << 4);

    const int start = rowptr[node];
    const int end   = rowptr[node + 1];

    f32x2 acc2[4];
#pragma unroll
    for (int j = 0; j < 4; ++j) acc2[j] = (f32x2){0.f, 0.f};

    const char* __restrict__ hbase = (const char*)Hb32;

    for (int b = start; b < end; b += 64) {
        int li = b + lane;
        unsigned rl = 0;
        if (li < end) rl = rec[li];
        int nb = end - b; if (nb > 64) nb = 64;
        for (int i = 0; i < nb; i += 16) {
            unsigned rA = __shfl(rl, i + sub,      64);
            unsigned rB = __shfl(rl, i + 4 + sub,  64);
            unsigned rC = __shfl(rl, i + 8 + sub,  64);
            unsigned rD = __shfl(rl, i + 12 + sub, 64);
            float nA = dtab[rA];
            float nB = dtab[rB];
            float nC = dtab[rC];
            float nD = dtab[rD];
            unsigned oA = rA ? (((rA - 1u) << 8) | dlo) : dlo;
            unsigned oB = rB ? (((rB - 1u) << 8) | dlo) : dlo;
            unsigned oC = rC ? (((rC - 1u) << 8) | dlo) : dlo;
            unsigned oD = rD ? (((rD - 1u) << 8) | dlo) : dlo;
            uint4 qA = *(const uint4*)(hbase + oA);
            uint4 qB = *(const uint4*)(hbase + oB);
            uint4 qC = *(const uint4*)(hbase + oC);
            uint4 qD = *(const uint4*)(hbase + oD);
            f32x2 nA2 = (f32x2){nA, nA};
            f32x2 nB2 = (f32x2){nB, nB};
            f32x2 nC2 = (f32x2){nC, nC};
            f32x2 nD2 = (f32x2){nD, nD};
            acc2[0] = __builtin_elementwise_fma(nA2, unpk2(qA.x), acc2[0]);
            acc2[1] = __builtin_elementwise_fma(nA2, unpk2(qA.y), acc2[1]);
            acc2[2] = __builtin_elementwise_fma(nA2, unpk2(qA.z), acc2[2]);
            acc2[3] = __builtin_elementwise_fma(nA2, unpk2(qA.w), acc2[3]);
            acc2[0] = __builtin_elementwise_fma(nB2, unpk2(qB.x), acc2[0]);
            acc2[1] = __builtin_elementwise_fma(nB2, unpk2(qB.y), acc2[1]);
            acc2[2] = __builtin_elementwise_fma(nB2, unpk2(qB.z), acc2[2]);
            acc2[3] = __builtin_elementwise_fma(nB2, unpk2(qB.w), acc2[3]);
            acc2[0] = __builtin_elementwise_fma(nC2, unpk2(qC.x), acc2[0]);
            acc2[1] = __builtin_elementwise_fma(nC2, unpk2(qC.y), acc2[1]);
            acc2[2] = __builtin_elementwise_fma(nC2, unpk2(qC.z), acc2[2]);
            acc2[3] = __builtin_elementwise_fma(nC2, unpk2(qC.w), acc2[3]);
            acc2[0] = __builtin_elementwise_fma(nD2, unpk2(qD.x), acc2[0]);
            acc2[1] = __builtin_elementwise_fma(nD2, unpk2(qD.y), acc2[1]);
            acc2[2] = __builtin_elementwise_fma(nD2, unpk2(qD.z), acc2[2]);
            acc2[3] = __builtin_elementwise_fma(nD2, unpk2(qD.w), acc2[3]);
        }
    }

    float acc[8];
#pragma unroll
    for (int j = 0; j < 4; ++j) { acc[2 * j] = acc2[j].x; acc[2 * j + 1] = acc2[j].y; }

#pragma unroll
    for (int j = 0; j < 8; ++j) {
        acc[j] += __shfl_xor(acc[j], 16, 64);
        acc[j] += __shfl_xor(acc[j], 32, 64);
    }

    if (sub == 0) {
        const float dd = dtab[node + 1];
        const float s2 = dd * dd;
        uint4 q = *(const uint4*)(hbase + (((unsigned)node << 8) | dlo));
        float o[8];
        o[0] = dd * acc[0] + s2 * bflo(q.x);
        o[1] = dd * acc[1] + s2 * bfhi(q.x);
        o[2] = dd * acc[2] + s2 * bflo(q.y);
        o[3] = dd * acc[3] + s2 * bfhi(q.y);
        o[4] = dd * acc[4] + s2 * bflo(q.z);
        o[5] = dd * acc[5] + s2 * bfhi(q.z);
        o[6] = dd * acc[6] + s2 * bflo(q.w);
        o[7] = dd * acc[7] + s2 * bfhi(q.w);

        float4 b0 = *(const float4*)&bias[dl * 8];
        float4 b1 = *(const float4*)&bias[dl * 8 + 4];
        o[0] += b0.x; o[1] += b0.y; o[2] += b0.z; o[3] += b0.w;
        o[4] += b1.x; o[5] += b1.y; o[6] += b1.z; o[7] += b1.w;

        if (STORE_BF16) {
            unsigned short* ob = (unsigned short*)outv;
            uint4 pk;
            pk.x = pk2bf(o[0], o[1]);
            pk.y = pk2bf(o[2], o[3]);
            pk.z = pk2bf(o[4], o[5]);
            pk.w = pk2bf(o[6], o[7]);
            *(uint4*)&ob[(size_t)node * EMB + dl * 8] = pk;
        } else {
            float* of = (float*)outv;
            *(float4*)&of[(size_t)node * EMB + dl * 8]     = make_float4(o[0], o[1], o[2], o[3]);
            *(float4*)&of[(size_t)node * EMB + dl * 8 + 4] = make_float4(o[4], o[5], o[6], o[7]);
        }
    }
}

// ---------------- launch ----------------

extern "C" void kernel_launch(void* const* d_in, const int* in_sizes, int n_in,
                              void* d_out, int out_size, void* d_ws, size_t ws_size,
                              hipStream_t stream) {
    const float* x  = (const float*)d_in[0];
    const float* W0 = (const float*)d_in[1];
    const float* b0 = (const float*)d_in[2];
    const float* W1 = (const float*)d_in[3];
    const float* b1 = (const float*)d_in[4];
    const int*   pos = (const int*)d_in[5];
    const int*   neg = (const int*)d_in[6];

    // workspace layout (4-byte word offsets) — end-offset audit:
    //   dtab    [0,        100001)
    //   hb      [100352,   6500352)    N*128 bf16 = 6.4M words
    //   rowptr  [6500352,  6600353)
    //   bcur    [6600356,  6600612)
    //   wbase   [6600612,  6600868)
    //   ptmp    [6600872,  8698024)    256*8192 words
    //   colidx  [8698024,  10298024)   1.6M words
    //   zb      [10298024, 16698024)   N*128 bf16 = 6.4M words
    //   wbg0    [16698024, 16706216)   8192 words   (AFTER zb — R18 bug fix)
    //   wbg1    [16706216, 16714408)   8192 words
    float* ws      = (float*)d_ws;
    float* dtab    = ws;
    unsigned short* hb = (unsigned short*)(ws + 100352);
    int*   rowptr  = (int*)(ws + 6500352);
    int*   bcur    = (int*)(ws + 6600356);
    int*   wbase   = (int*)(ws + 6600612);
    unsigned* ptmp = (unsigned*)(ws + 6600872);
    unsigned* colidx = (unsigned*)(ws + 8698024);
    unsigned short* zb = (unsigned short*)(ws + 10298024);
    unsigned* wbg0 = (unsigned*)(ws + 16698024);
    unsigned* wbg1 = (unsigned*)(ws + 16706216);

    // ---- CSR build (shared by both layers) ----
    binit_kernel<<<1, NWIN, 0, stream>>>(bcur);
    binA_kernel<<<ABLOCKS, 256, 0, stream>>>(pos, neg, bcur, ptmp);
    wscan_kernel<<<1, NWIN, 0, stream>>>(bcur, wbase);
    binCB_kernel<<<NWIN, 1024, 0, stream>>>(bcur, wbase, ptmp, rowptr, dtab, colidx);

    // ---- W pre-swizzle (both layers) ----
    wprep_kernel<<<32, 256, 0, stream>>>(W0, wbg0);
    wprep_kernel<<<32, 256, 0, stream>>>(W1, wbg1);

    const int agg_grid  = (N_NODES + AGG_WAVES - 1) / AGG_WAVES;
    const int gemm_grid = (N_NODES + GROWS - 1) / GROWS;

    // ---- layer 0: h0 = bf16(x@W0); z0(bf16) = agg(h0) + b0 ----
    gemm_kernel<false><<<gemm_grid, 256, 0, stream>>>(x, wbg0, hb);
    aggregate_kernel<true><<<agg_grid, 256, 0, stream>>>(
        rowptr, colidx, (const unsigned*)hb, dtab, b0, zb);

    // ---- layer 1: h1 = bf16(z0@W1); out(f32) = agg(h1) + b1 ----
    gemm_kernel<true><<<gemm_grid, 256, 0, stream>>>(zb, wbg1, hb);
    aggregate_kernel<false><<<agg_grid, 256, 0, stream>>>(
        rowptr, colidx, (const unsigned*)hb, dtab, b1, d_out);
}